// Round 4
// baseline (80.113 us; speedup 1.0000x reference)
//
#include <hip/hip_runtime.h>
#include <stdint.h>

// ---------------------------------------------------------------------------
// BondMatrixMessage: messages[b,e,i] = sum_{k,j} bond[b,e,k] W[k,i,j] src[b,e,j]
// GEMM recast: C[16384 x 64] = A[16384 x 4096] @ W2[4096 x 64]
//   A[e, k*64+j] = bond[e,k]*src[e,j]  (registers, v_pk_mul_f16)
//   W2 prep-cast to f16 in MFMA-fragment order -> main-loop B loads are
//   coalesced global_load_dwordx4 direct to registers.
// 256 blocks x 256 thr; 4 waves = 2 col-halves (wc) x 2 k-halves (kh);
// v_mfma_f32_32x32x16_f16, kh pair-reduced via LDS at the end.
// R4: DIAGNOSTIC build. REPS=8 repeats of the main loop (DCE-defeated by a
// runtime-true re-zero) to push bond_msg into the rocprof top-5 and obtain
// MfmaUtil/VALUBusy/conflict counters. Also: 4-buffer register ring with
// loads issued 3 COMPITs (~400 cyc) ahead (covers L2 latency, ~48KB/CU in
// flight), and bondT ds_reads software-pipelined 1 COMPIT ahead.
// ---------------------------------------------------------------------------

#define NATOMS 256
#define DIM 64
#define BM 64
#define REPS 8   // diagnostic repeat; set to 1 for production

typedef _Float16 f16;
typedef _Float16 f16x2 __attribute__((ext_vector_type(2)));
typedef _Float16 f16x8 __attribute__((ext_vector_type(8)));
typedef float f32x16 __attribute__((ext_vector_type(16)));

#define AS1 __attribute__((address_space(1)))
#define AS3 __attribute__((address_space(3)))

union H8 { f16x8 v8; f16x2 v2[4]; };

static __device__ __forceinline__ void gll16(const void* g, void* l) {
    __builtin_amdgcn_global_load_lds((AS1 void*)(uintptr_t)g, (AS3 void*)l, 16, 0, 0);
}

// prep: cast + permute bt (64 x 4096 f32) into fragment-ordered f16 chunks.
// Chunk (kg, wc, s, l): bt[kg][i*64 + u*8 .. +8], i=(l&31)+32*wc, u=2*s+(l>>5).
__global__ __launch_bounds__(256) void prep_w2f(const float* __restrict__ bt,
                                                f16* __restrict__ w2f) {
    const int d  = blockIdx.x * 256 + threadIdx.x;   // 32768 chunks
    const int kg = d >> 9, c = d & 511;
    const int wcq = c >> 8, s = (c >> 6) & 3, l = c & 63;
    const int i = (l & 31) + 32 * wcq;
    const int u = 2 * s + (l >> 5);
    const float* src = bt + (size_t)kg * 4096 + i * 64 + u * 8;
    const float4 p = *reinterpret_cast<const float4*>(src);
    const float4 q = *reinterpret_cast<const float4*>(src + 4);
    const f16x8 h = { (f16)p.x, (f16)p.y, (f16)p.z, (f16)p.w,
                      (f16)q.x, (f16)q.y, (f16)q.z, (f16)q.w };
    reinterpret_cast<f16x8*>(w2f)[d] = h;
}

__global__ __launch_bounds__(256, 1) void bond_msg(
    const float* __restrict__ atom, const float* __restrict__ bond,
    const int* __restrict__ conn, const f16* __restrict__ w2f,
    float* __restrict__ out)
{
    // LDS: [0,16KB) raw bond tile f32[m][k] -> reused as kh-reduce buffer
    //      [16KB,32KB) bondT dup'd-f16 u32[64][64] (m XOR-swizzled)
    __shared__ __align__(16) unsigned char smem[32768];

    const int tid  = threadIdx.x;
    const int lane = tid & 63;
    const int w    = tid >> 6;
    const int wc   = w & 1;        // column half (i: 0-31 / 32-63)
    const int kh   = w >> 1;       // k half
    const int lo   = lane & 31;
    const int hi   = lane >> 5;
    const int blk  = blockIdx.x;
    const int bond0 = blk * BM;

    // ---- src atom gather -> registers (f16 pairs). Rows m0=lo, m1=lo+32.
    const int m0 = lo, m1 = lo + 32;
    const int ia0 = conn[(bond0 + m0) * 2];
    const int ia1 = conn[(bond0 + m1) * 2];
    const float* ar0 = atom + (size_t)(blk >> 3) * (NATOMS * DIM) + (size_t)ia0 * DIM;
    const float* ar1 = atom + (size_t)(blk >> 3) * (NATOMS * DIM) + (size_t)ia1 * DIM;
    f16x2 srcv[2][4][4];   // [m-frag][s][pair]; j = s*16 + hi*8 + {0..7}
    #pragma unroll
    for (int s = 0; s < 4; ++s) {
        const int j0 = s * 16 + hi * 8;
        float4 p0 = *reinterpret_cast<const float4*>(ar0 + j0);
        float4 p1 = *reinterpret_cast<const float4*>(ar0 + j0 + 4);
        float4 q0 = *reinterpret_cast<const float4*>(ar1 + j0);
        float4 q1 = *reinterpret_cast<const float4*>(ar1 + j0 + 4);
        srcv[0][s][0] = (f16x2){ (f16)p0.x, (f16)p0.y };
        srcv[0][s][1] = (f16x2){ (f16)p0.z, (f16)p0.w };
        srcv[0][s][2] = (f16x2){ (f16)p1.x, (f16)p1.y };
        srcv[0][s][3] = (f16x2){ (f16)p1.z, (f16)p1.w };
        srcv[1][s][0] = (f16x2){ (f16)q0.x, (f16)q0.y };
        srcv[1][s][1] = (f16x2){ (f16)q0.z, (f16)q0.w };
        srcv[1][s][2] = (f16x2){ (f16)q1.x, (f16)q1.y };
        srcv[1][s][3] = (f16x2){ (f16)q1.z, (f16)q1.w };
    }

    // ---- prologue: stage raw bond tile, transpose to dup'd-f16 bondT
    {
        const char* gb = reinterpret_cast<const char*>(bond + (size_t)bond0 * DIM);
        #pragma unroll
        for (int c = 0; c < 4; ++c)
            gll16(gb + w * 4096 + c * 1024 + lane * 16, smem + w * 4096 + c * 1024);
    }
    __syncthreads();
    {
        const float* bl = reinterpret_cast<const float*>(smem);
        unsigned* btw = reinterpret_cast<unsigned*>(smem + 16384);
        const int k = lane;
        #pragma unroll
        for (int mm = 0; mm < 16; ++mm) {
            const int m = w * 16 + mm;
            const f16 hh = (f16)bl[m * 64 + k];
            const f16x2 d = { hh, hh };
            btw[k * 64 + (m ^ (k & 31))] = __builtin_bit_cast(unsigned, d);
        }
    }
    __syncthreads();

    // ---- main loop: barrier-free; 4-buffer register ring (3-deep shadow)
    const unsigned* btl = reinterpret_cast<const unsigned*>(smem + 16384);
    const char* gw = reinterpret_cast<const char*>(w2f)
                   + (size_t)kh * 32 * 8192 + wc * 4096 + lane * 16;

    f16x8 b0[4], b1[4], b2[4], b3[4];
    f32x16 acc0, acc1;
    f16x2 pA0, pA1, pB0, pB1;            // bondT pairs, pipelined 1 ahead
    const bool opq = (ia0 > -2000000000); // runtime-true: defeats rep DCE

    #define LOADIT(buf, itw) do {                                         \
        const char* _p = gw + (itw) * 8192;                               \
        buf[0] = *reinterpret_cast<const f16x8*>(_p);                     \
        buf[1] = *reinterpret_cast<const f16x8*>(_p + 1024);              \
        buf[2] = *reinterpret_cast<const f16x8*>(_p + 2048);              \
        buf[3] = *reinterpret_cast<const f16x8*>(_p + 3072);              \
    } while (0)

    #define BLOAD(d0, d1, iti) do {                                      \
        const int _kg = kh * 32 + ((iti) & 31);                          \
        d0 = __builtin_bit_cast(f16x2, btl[_kg * 64 + (m0 ^ (_kg & 31))]);\
        d1 = __builtin_bit_cast(f16x2, btl[_kg * 64 + (m1 ^ (_kg & 31))]);\
    } while (0)

    // compute with (cb0,cb1); prefetch bond pair for itn into (nb0,nb1)
    #define COMPIT(buf, cb0, cb1, nb0, nb1, itn) do {                     \
        BLOAD(nb0, nb1, itn);                                             \
        _Pragma("unroll")                                                 \
        for (int s = 0; s < 4; ++s) {                                     \
            H8 _a0, _a1;                                                  \
            _Pragma("unroll")                                             \
            for (int t = 0; t < 4; ++t) {                                 \
                _a0.v2[t] = cb0 * srcv[0][s][t];                          \
                _a1.v2[t] = cb1 * srcv[1][s][t];                          \
            }                                                             \
            acc0 = __builtin_amdgcn_mfma_f32_32x32x16_f16(_a0.v8, buf[s], acc0, 0, 0, 0); \
            acc1 = __builtin_amdgcn_mfma_f32_32x32x16_f16(_a1.v8, buf[s], acc1, 0, 0, 0); \
        }                                                                 \
    } while (0)

    LOADIT(b0, 0); LOADIT(b1, 1); LOADIT(b2, 2);
    BLOAD(pA0, pA1, 0);
    acc0 = (f32x16){}; acc1 = (f32x16){};

    for (int rep = 0; rep < REPS; ++rep) {
        if (opq) { acc0 = (f32x16){}; acc1 = (f32x16){}; }
        for (int it = 0; it < 32; it += 4) {
            LOADIT(b3, (it + 3) & 31);
            COMPIT(b0, pA0, pA1, pB0, pB1, it + 1);
            LOADIT(b0, (it + 4) & 31);
            COMPIT(b1, pB0, pB1, pA0, pA1, it + 2);
            LOADIT(b1, (it + 5) & 31);
            COMPIT(b2, pA0, pA1, pB0, pB1, it + 3);
            LOADIT(b2, (it + 6) & 31);
            COMPIT(b3, pB0, pB1, pA0, pA1, it + 4);   // wraps -> next rep's it=0
        }
    }

    // ---- epilogue: reduce k-halves through LDS, write C
    if (kh == 1) {
        #pragma unroll
        for (int g = 0; g < 4; ++g) {
            float4 v0 = { acc0[4*g+0], acc0[4*g+1], acc0[4*g+2], acc0[4*g+3] };
            *reinterpret_cast<float4*>(smem + wc*8192 + g*1024 + lane*16) = v0;
            float4 v1 = { acc1[4*g+0], acc1[4*g+1], acc1[4*g+2], acc1[4*g+3] };
            *reinterpret_cast<float4*>(smem + wc*8192 + (g+4)*1024 + lane*16) = v1;
        }
    }
    __syncthreads();
    if (kh == 0) {
        #pragma unroll
        for (int g = 0; g < 4; ++g) {
            float4 v0 = *reinterpret_cast<const float4*>(smem + wc*8192 + g*1024 + lane*16);
            acc0[4*g+0] += v0.x; acc0[4*g+1] += v0.y; acc0[4*g+2] += v0.z; acc0[4*g+3] += v0.w;
            float4 v1 = *reinterpret_cast<const float4*>(smem + wc*8192 + (g+4)*1024 + lane*16);
            acc1[4*g+0] += v1.x; acc1[4*g+1] += v1.y; acc1[4*g+2] += v1.z; acc1[4*g+3] += v1.w;
        }
        const int colb = 32 * wc + lo;
        #pragma unroll
        for (int r = 0; r < 16; ++r) {
            const int rl = (r & 3) + 8 * (r >> 2) + 4 * hi;
            out[(size_t)(bond0 + rl) * 64 + colb]      = acc0[r];
            out[(size_t)(bond0 + 32 + rl) * 64 + colb] = acc1[r];
        }
    }
    #undef LOADIT
    #undef BLOAD
    #undef COMPIT
}

// ---- fallback (ws too small): f32, LDS-staged, correct.
__global__ __launch_bounds__(256) void bond_fallback(
    const float* __restrict__ atom, const float* __restrict__ bond,
    const int* __restrict__ conn, const float* __restrict__ bt,
    float* __restrict__ out)
{
    __shared__ float Wk[4096];
    __shared__ float srcs[4][64];
    __shared__ float bnds[4][64];
    const int blk = blockIdx.x;
    const int e0 = blk * 4;
    const int b = e0 >> 9;
    const int t = threadIdx.x;
    const int il = t & 63, eg = t >> 6;
    const int e = e0 + eg;
    const int ia = conn[e * 2];
    srcs[eg][il] = atom[(size_t)b * (NATOMS * DIM) + (size_t)ia * DIM + il];
    bnds[eg][il] = bond[(size_t)e * DIM + il];
    float acc = 0.f;
    for (int k = 0; k < 64; ++k) {
        __syncthreads();
        #pragma unroll
        for (int c = 0; c < 4; ++c) {
            float4 v = reinterpret_cast<const float4*>(bt + (size_t)k * 4096)[t + c * 256];
            reinterpret_cast<float4*>(Wk)[t + c * 256] = v;
        }
        __syncthreads();
        float s = 0.f;
        #pragma unroll
        for (int j = 0; j < 64; ++j) s += Wk[il * 64 + j] * srcs[eg][j];
        acc += bnds[eg][k] * s;
    }
    out[(size_t)e * DIM + il] = acc;
}

extern "C" void kernel_launch(void* const* d_in, const int* in_sizes, int n_in,
                              void* d_out, int out_size, void* d_ws, size_t ws_size,
                              hipStream_t stream) {
    const float* atom = (const float*)d_in[0];   // (32,256,64) f32
    const float* bond = (const float*)d_in[1];   // (32,512,64) f32
    const int*   conn = (const int*)d_in[2];     // (32,512,2) int32 (narrowed)
    const float* bt   = (const float*)d_in[3];   // (64,4096) f32
    float* out = (float*)d_out;                  // (32,512,64) f32

    if (ws_size >= (size_t)64 * 4096 * sizeof(f16)) {
        f16* w2f = (f16*)d_ws;                   // 512 KB scratch
        prep_w2f<<<128, 256, 0, stream>>>(bt, w2f);
        bond_msg<<<256, 256, 0, stream>>>(atom, bond, conn, w2f, out);
    } else {
        bond_fallback<<<4096, 256, 0, stream>>>(atom, bond, conn, bt, out);
    }
}

// Round 5
// 23.604 us; speedup vs baseline: 3.3941x; 3.3941x over previous
//
#include <hip/hip_runtime.h>
#include <stdint.h>

// ---------------------------------------------------------------------------
// BondMatrixMessage: messages[b,e,i] = sum_{k,j} bond[b,e,k] W[k,i,j] src[b,e,j]
// GEMM recast: C[16384 x 64] = A[16384 x 4096] @ W2[4096 x 64]
//   A[e, k*64+j] = bond[e,k]*src[e,j]  (registers, v_pk_mul_f16)
//   W2 prep-cast to f16 in MFMA-fragment order -> main-loop B loads are
//   coalesced global_load_dwordx4 direct to registers.
// R5: 256 blocks x 512 thr (8 waves = 2 waves/SIMD). Waves = 2 col-halves
// (wc) x 4 k-quarters (kq), 16 iters each. R4 diagnostic showed 1 wave/SIMD
// caps MfmaUtil at 45% (acc dependency chain + nothing to overlap); second
// wave per SIMD supplies the TLP. kq partials reduced via LDS at the end.
// Main loop stays barrier-free; 4-buffer register ring.
// conn is int32 (harness narrows int64): src idx = conn[e*2].
// ---------------------------------------------------------------------------

#define NATOMS 256
#define DIM 64
#define BM 64

typedef _Float16 f16;
typedef _Float16 f16x2 __attribute__((ext_vector_type(2)));
typedef _Float16 f16x8 __attribute__((ext_vector_type(8)));
typedef float f32x16 __attribute__((ext_vector_type(16)));

#define AS1 __attribute__((address_space(1)))
#define AS3 __attribute__((address_space(3)))

union H8 { f16x8 v8; f16x2 v2[4]; };

static __device__ __forceinline__ void gll16(const void* g, void* l) {
    __builtin_amdgcn_global_load_lds((AS1 void*)(uintptr_t)g, (AS3 void*)l, 16, 0, 0);
}

// prep: cast + permute bt (64 x 4096 f32) into fragment-ordered f16 chunks.
// Chunk (kg, wc, s, l): bt[kg][i*64 + u*8 .. +8], i=(l&31)+32*wc, u=2*s+(l>>5).
__global__ __launch_bounds__(256) void prep_w2f(const float* __restrict__ bt,
                                                f16* __restrict__ w2f) {
    const int d  = blockIdx.x * 256 + threadIdx.x;   // 32768 chunks
    const int kg = d >> 9, c = d & 511;
    const int wcq = c >> 8, s = (c >> 6) & 3, l = c & 63;
    const int i = (l & 31) + 32 * wcq;
    const int u = 2 * s + (l >> 5);
    const float* src = bt + (size_t)kg * 4096 + i * 64 + u * 8;
    const float4 p = *reinterpret_cast<const float4*>(src);
    const float4 q = *reinterpret_cast<const float4*>(src + 4);
    const f16x8 h = { (f16)p.x, (f16)p.y, (f16)p.z, (f16)p.w,
                      (f16)q.x, (f16)q.y, (f16)q.z, (f16)q.w };
    reinterpret_cast<f16x8*>(w2f)[d] = h;
}

__global__ __launch_bounds__(512) void bond_msg(
    const float* __restrict__ atom, const float* __restrict__ bond,
    const int* __restrict__ conn, const f16* __restrict__ w2f,
    float* __restrict__ out)
{
    // LDS: [0,16K) raw bond tile (prologue only) -> dead after transpose
    //      [0,48K)  kq-reduce buffer (epilogue only; 6 waves x 8KB)
    //      [48K,64K) bondT dup'd-f16 u32[64][64] (m XOR-swizzled) -- live all
    __shared__ __align__(16) unsigned char smem[65536];

    const int tid  = threadIdx.x;
    const int lane = tid & 63;
    const int w    = tid >> 6;     // wave 0..7
    const int wc   = w & 1;        // column half (i: 0-31 / 32-63)
    const int kq   = w >> 1;       // k quarter (16 k-values each)
    const int lo   = lane & 31;
    const int hi   = lane >> 5;
    const int blk  = blockIdx.x;
    const int bond0 = blk * BM;    // 8 blocks per batch; never straddles

    // ---- src atom gather -> registers (f16 pairs). Rows m0=lo, m1=lo+32.
    const int m0 = lo, m1 = lo + 32;
    const int ia0 = conn[(bond0 + m0) * 2];
    const int ia1 = conn[(bond0 + m1) * 2];
    const float* ar0 = atom + (size_t)(blk >> 3) * (NATOMS * DIM) + (size_t)ia0 * DIM;
    const float* ar1 = atom + (size_t)(blk >> 3) * (NATOMS * DIM) + (size_t)ia1 * DIM;
    f16x2 srcv[2][4][4];   // [m-frag][s][pair]; j = s*16 + hi*8 + {0..7}
    #pragma unroll
    for (int s = 0; s < 4; ++s) {
        const int j0 = s * 16 + hi * 8;
        float4 p0 = *reinterpret_cast<const float4*>(ar0 + j0);
        float4 p1 = *reinterpret_cast<const float4*>(ar0 + j0 + 4);
        float4 q0 = *reinterpret_cast<const float4*>(ar1 + j0);
        float4 q1 = *reinterpret_cast<const float4*>(ar1 + j0 + 4);
        srcv[0][s][0] = (f16x2){ (f16)p0.x, (f16)p0.y };
        srcv[0][s][1] = (f16x2){ (f16)p0.z, (f16)p0.w };
        srcv[0][s][2] = (f16x2){ (f16)p1.x, (f16)p1.y };
        srcv[0][s][3] = (f16x2){ (f16)p1.z, (f16)p1.w };
        srcv[1][s][0] = (f16x2){ (f16)q0.x, (f16)q0.y };
        srcv[1][s][1] = (f16x2){ (f16)q0.z, (f16)q0.w };
        srcv[1][s][2] = (f16x2){ (f16)q1.x, (f16)q1.y };
        srcv[1][s][3] = (f16x2){ (f16)q1.z, (f16)q1.w };
    }

    // ---- prologue: stage raw bond tile (16KB), transpose to dup'd-f16 bondT
    {
        const char* gb = reinterpret_cast<const char*>(bond + (size_t)bond0 * DIM);
        #pragma unroll
        for (int c = 0; c < 2; ++c)
            gll16(gb + w * 2048 + c * 1024 + lane * 16, smem + w * 2048 + c * 1024);
    }
    __syncthreads();   // drains gll vmcnt
    {
        const float* bl = reinterpret_cast<const float*>(smem);
        unsigned* btw = reinterpret_cast<unsigned*>(smem + 49152);
        const int k = lane;
        #pragma unroll
        for (int mm = 0; mm < 8; ++mm) {
            const int m = w * 8 + mm;
            const f16 hh = (f16)bl[m * 64 + k];
            const f16x2 d = { hh, hh };
            btw[k * 64 + (m ^ (k & 31))] = __builtin_bit_cast(unsigned, d);
        }
    }
    __syncthreads();

    // ---- main loop: barrier-free; 4-buffer register ring; 16 iters/wave
    const unsigned* btl = reinterpret_cast<const unsigned*>(smem + 49152);
    const char* gw = reinterpret_cast<const char*>(w2f)
                   + (size_t)kq * 16 * 8192 + wc * 4096 + lane * 16;

    f16x8 b0[4], b1[4], b2[4], b3[4];
    f32x16 acc0, acc1;
    f16x2 pA0, pA1, pB0, pB1;            // bondT pairs, pipelined 1 ahead

    #define LOADIT(buf, itw) do {                                         \
        const char* _p = gw + (itw) * 8192;                               \
        buf[0] = *reinterpret_cast<const f16x8*>(_p);                     \
        buf[1] = *reinterpret_cast<const f16x8*>(_p + 1024);              \
        buf[2] = *reinterpret_cast<const f16x8*>(_p + 2048);              \
        buf[3] = *reinterpret_cast<const f16x8*>(_p + 3072);              \
    } while (0)

    #define BLOAD(d0, d1, iti) do {                                      \
        const int _kg = kq * 16 + ((iti) & 15);                          \
        d0 = __builtin_bit_cast(f16x2, btl[_kg * 64 + (m0 ^ (_kg & 31))]);\
        d1 = __builtin_bit_cast(f16x2, btl[_kg * 64 + (m1 ^ (_kg & 31))]);\
    } while (0)

    #define COMPIT(buf, cb0, cb1, nb0, nb1, itn) do {                     \
        BLOAD(nb0, nb1, itn);                                             \
        _Pragma("unroll")                                                 \
        for (int s = 0; s < 4; ++s) {                                     \
            H8 _a0, _a1;                                                  \
            _Pragma("unroll")                                             \
            for (int t = 0; t < 4; ++t) {                                 \
                _a0.v2[t] = cb0 * srcv[0][s][t];                          \
                _a1.v2[t] = cb1 * srcv[1][s][t];                          \
            }                                                             \
            acc0 = __builtin_amdgcn_mfma_f32_32x32x16_f16(_a0.v8, buf[s], acc0, 0, 0, 0); \
            acc1 = __builtin_amdgcn_mfma_f32_32x32x16_f16(_a1.v8, buf[s], acc1, 0, 0, 0); \
        }                                                                 \
    } while (0)

    LOADIT(b0, 0); LOADIT(b1, 1); LOADIT(b2, 2);
    BLOAD(pA0, pA1, 0);
    acc0 = (f32x16){}; acc1 = (f32x16){};

    for (int it = 0; it < 16; it += 4) {
        LOADIT(b3, (it + 3) & 15);
        COMPIT(b0, pA0, pA1, pB0, pB1, it + 1);
        LOADIT(b0, (it + 4) & 15);
        COMPIT(b1, pB0, pB1, pA0, pA1, it + 2);
        LOADIT(b1, (it + 5) & 15);
        COMPIT(b2, pA0, pA1, pB0, pB1, it + 3);
        LOADIT(b2, (it + 6) & 15);
        COMPIT(b3, pB0, pB1, pA0, pA1, it + 4);
    }

    // ---- epilogue: 4-way kq reduce through LDS [0,48K), kq=0 writes C
    if (kq != 0) {
        const unsigned rbase = (unsigned)(((kq - 1) * 2 + wc) * 8192);
        #pragma unroll
        for (int g = 0; g < 4; ++g) {
            float4 v0 = { acc0[4*g+0], acc0[4*g+1], acc0[4*g+2], acc0[4*g+3] };
            *reinterpret_cast<float4*>(smem + rbase + g*1024 + lane*16) = v0;
            float4 v1 = { acc1[4*g+0], acc1[4*g+1], acc1[4*g+2], acc1[4*g+3] };
            *reinterpret_cast<float4*>(smem + rbase + (g+4)*1024 + lane*16) = v1;
        }
    }
    __syncthreads();
    if (kq == 0) {
        #pragma unroll
        for (int q = 0; q < 3; ++q) {
            const unsigned rbase = (unsigned)((q * 2 + wc) * 8192);
            #pragma unroll
            for (int g = 0; g < 4; ++g) {
                float4 v0 = *reinterpret_cast<const float4*>(smem + rbase + g*1024 + lane*16);
                acc0[4*g+0] += v0.x; acc0[4*g+1] += v0.y; acc0[4*g+2] += v0.z; acc0[4*g+3] += v0.w;
                float4 v1 = *reinterpret_cast<const float4*>(smem + rbase + (g+4)*1024 + lane*16);
                acc1[4*g+0] += v1.x; acc1[4*g+1] += v1.y; acc1[4*g+2] += v1.z; acc1[4*g+3] += v1.w;
            }
        }
        const int colb = 32 * wc + lo;
        #pragma unroll
        for (int r = 0; r < 16; ++r) {
            // C/D map: col = lane&31, row = (r&3) + 8*(r>>2) + 4*(lane>>5)
            const int rl = (r & 3) + 8 * (r >> 2) + 4 * hi;
            out[(size_t)(bond0 + rl) * 64 + colb]      = acc0[r];
            out[(size_t)(bond0 + 32 + rl) * 64 + colb] = acc1[r];
        }
    }
    #undef LOADIT
    #undef BLOAD
    #undef COMPIT
}

// ---- fallback (ws too small): f32, LDS-staged, correct.
__global__ __launch_bounds__(256) void bond_fallback(
    const float* __restrict__ atom, const float* __restrict__ bond,
    const int* __restrict__ conn, const float* __restrict__ bt,
    float* __restrict__ out)
{
    __shared__ float Wk[4096];
    __shared__ float srcs[4][64];
    __shared__ float bnds[4][64];
    const int blk = blockIdx.x;
    const int e0 = blk * 4;
    const int b = e0 >> 9;
    const int t = threadIdx.x;
    const int il = t & 63, eg = t >> 6;
    const int e = e0 + eg;
    const int ia = conn[e * 2];
    srcs[eg][il] = atom[(size_t)b * (NATOMS * DIM) + (size_t)ia * DIM + il];
    bnds[eg][il] = bond[(size_t)e * DIM + il];
    float acc = 0.f;
    for (int k = 0; k < 64; ++k) {
        __syncthreads();
        #pragma unroll
        for (int c = 0; c < 4; ++c) {
            float4 v = reinterpret_cast<const float4*>(bt + (size_t)k * 4096)[t + c * 256];
            reinterpret_cast<float4*>(Wk)[t + c * 256] = v;
        }
        __syncthreads();
        float s = 0.f;
        #pragma unroll
        for (int j = 0; j < 64; ++j) s += Wk[il * 64 + j] * srcs[eg][j];
        acc += bnds[eg][k] * s;
    }
    out[(size_t)e * DIM + il] = acc;
}

extern "C" void kernel_launch(void* const* d_in, const int* in_sizes, int n_in,
                              void* d_out, int out_size, void* d_ws, size_t ws_size,
                              hipStream_t stream) {
    const float* atom = (const float*)d_in[0];   // (32,256,64) f32
    const float* bond = (const float*)d_in[1];   // (32,512,64) f32
    const int*   conn = (const int*)d_in[2];     // (32,512,2) int32 (narrowed)
    const float* bt   = (const float*)d_in[3];   // (64,4096) f32
    float* out = (float*)d_out;                  // (32,512,64) f32

    if (ws_size >= (size_t)64 * 4096 * sizeof(f16)) {
        f16* w2f = (f16*)d_ws;                   // 512 KB scratch
        prep_w2f<<<128, 256, 0, stream>>>(bt, w2f);
        bond_msg<<<256, 512, 0, stream>>>(atom, bond, conn, w2f, out);
    } else {
        bond_fallback<<<4096, 256, 0, stream>>>(atom, bond, conn, bt, out);
    }
}

// Round 6
// 22.920 us; speedup vs baseline: 3.4953x; 1.0298x over previous
//
#include <hip/hip_runtime.h>
#include <stdint.h>

// ---------------------------------------------------------------------------
// BondMatrixMessage: messages[b,e,i] = sum_{k,j} bond[b,e,k] W[k,i,j] src[b,e,j]
// GEMM recast: C[16384 x 64] = A[16384 x 4096] @ W2[4096 x 64]
//   A[e, k*64+j] = bond[e,k]*src[e,j]  (registers, v_pk_mul_f16)
//   W2 prep-cast to f16 in MFMA-fragment order -> main-loop B loads are
//   coalesced global_load_dwordx4 direct to registers.
// R6: F-elimination. R4 REPS decomposition gave main-loop ~8 us + ~12 us
// FIXED cost (LDS bond staging/transpose, 3 barriers, 2-of-8-wave epilogue).
// Now: bond k-slices loaded straight to registers (no LDS, no barriers before
// the loop), main loop LDS-free, epilogue parallel across all 512 threads
// with ONE barrier. 256 blocks x 512 thr (2 waves/SIMD for TLP);
// waves = 2 col-halves (wc) x 4 k-quarters (kq); kq partials LDS-reduced.
// conn is int32 (harness narrows int64): src idx = conn[e*2].
// ---------------------------------------------------------------------------

#define NATOMS 256
#define DIM 64
#define BM 64

typedef _Float16 f16;
typedef _Float16 f16x2 __attribute__((ext_vector_type(2)));
typedef _Float16 f16x8 __attribute__((ext_vector_type(8)));
typedef float f32x16 __attribute__((ext_vector_type(16)));

union H8 { f16x8 v8; f16x2 v2[4]; };

// prep: cast + permute bt (64 x 4096 f32) into fragment-ordered f16 chunks.
// Chunk (kg, wc, s, l): bt[kg][i*64 + u*8 .. +8], i=(l&31)+32*wc, u=2*s+(l>>5).
__global__ __launch_bounds__(256) void prep_w2f(const float* __restrict__ bt,
                                                f16* __restrict__ w2f) {
    const int d  = blockIdx.x * 256 + threadIdx.x;   // 32768 chunks
    const int kg = d >> 9, c = d & 511;
    const int wcq = c >> 8, s = (c >> 6) & 3, l = c & 63;
    const int i = (l & 31) + 32 * wcq;
    const int u = 2 * s + (l >> 5);
    const float* src = bt + (size_t)kg * 4096 + i * 64 + u * 8;
    const float4 p = *reinterpret_cast<const float4*>(src);
    const float4 q = *reinterpret_cast<const float4*>(src + 4);
    const f16x8 h = { (f16)p.x, (f16)p.y, (f16)p.z, (f16)p.w,
                      (f16)q.x, (f16)q.y, (f16)q.z, (f16)q.w };
    reinterpret_cast<f16x8*>(w2f)[d] = h;
}

static __device__ __forceinline__ unsigned swz16(unsigned lane) {
    // 16B-granular XOR swizzle: bijective, makes 64-lane b128 stores over a
    // 1KB row conflict-free (banks = (lane low3) ^ (lane high3)).
    return (lane * 16u) ^ ((lane & 0x38u) << 1);
}

__global__ __launch_bounds__(512, 2) void bond_msg(
    const float* __restrict__ atom, const float* __restrict__ bond,
    const int* __restrict__ conn, const f16* __restrict__ w2f,
    float* __restrict__ out)
{
    // LDS: epilogue partials ONLY. [w][a*4+g][swz(lane)] : 8 waves x 8KB.
    __shared__ __align__(16) unsigned char smem[65536];

    const int tid  = threadIdx.x;
    const int lane = tid & 63;
    const int w    = tid >> 6;     // wave 0..7
    const int wc   = w & 1;        // column half (i: 0-31 / 32-63)
    const int kq   = w >> 1;       // k quarter (16 k-values each)
    const int lo   = lane & 31;
    const int hi   = lane >> 5;
    const int blk  = blockIdx.x;
    const int bond0 = blk * BM;    // 8 blocks per batch; never straddles

    // ---- conn (only dependency chain: conn -> src gather)
    const int m0 = lo, m1 = lo + 32;
    const int ia0 = conn[(bond0 + m0) * 2];
    const int ia1 = conn[(bond0 + m1) * 2];

    // ---- bond k-slices straight to registers (independent of conn)
    // lane needs bond[bond0+m][kq*16 .. +16) for m = m0, m1
    f16x2 bp0[16], bp1[16];
    {
        const float* br0 = bond + (size_t)(bond0 + m0) * DIM + kq * 16;
        const float* br1 = bond + (size_t)(bond0 + m1) * DIM + kq * 16;
        #pragma unroll
        for (int q = 0; q < 4; ++q) {
            const float4 v0 = *reinterpret_cast<const float4*>(br0 + q * 4);
            const float4 v1 = *reinterpret_cast<const float4*>(br1 + q * 4);
            const f16 a0 = (f16)v0.x, a1 = (f16)v0.y, a2 = (f16)v0.z, a3 = (f16)v0.w;
            const f16 c0 = (f16)v1.x, c1 = (f16)v1.y, c2 = (f16)v1.z, c3 = (f16)v1.w;
            bp0[q*4+0] = (f16x2){a0,a0}; bp0[q*4+1] = (f16x2){a1,a1};
            bp0[q*4+2] = (f16x2){a2,a2}; bp0[q*4+3] = (f16x2){a3,a3};
            bp1[q*4+0] = (f16x2){c0,c0}; bp1[q*4+1] = (f16x2){c1,c1};
            bp1[q*4+2] = (f16x2){c2,c2}; bp1[q*4+3] = (f16x2){c3,c3};
        }
    }

    // ---- src atom gather -> registers (f16 pairs)
    const float* ar0 = atom + (size_t)(blk >> 3) * (NATOMS * DIM) + (size_t)ia0 * DIM;
    const float* ar1 = atom + (size_t)(blk >> 3) * (NATOMS * DIM) + (size_t)ia1 * DIM;
    f16x2 srcv[2][4][4];   // [m-frag][s][pair]; j = s*16 + hi*8 + {0..7}
    #pragma unroll
    for (int s = 0; s < 4; ++s) {
        const int j0 = s * 16 + hi * 8;
        float4 p0 = *reinterpret_cast<const float4*>(ar0 + j0);
        float4 p1 = *reinterpret_cast<const float4*>(ar0 + j0 + 4);
        float4 q0 = *reinterpret_cast<const float4*>(ar1 + j0);
        float4 q1 = *reinterpret_cast<const float4*>(ar1 + j0 + 4);
        srcv[0][s][0] = (f16x2){ (f16)p0.x, (f16)p0.y };
        srcv[0][s][1] = (f16x2){ (f16)p0.z, (f16)p0.w };
        srcv[0][s][2] = (f16x2){ (f16)p1.x, (f16)p1.y };
        srcv[0][s][3] = (f16x2){ (f16)p1.z, (f16)p1.w };
        srcv[1][s][0] = (f16x2){ (f16)q0.x, (f16)q0.y };
        srcv[1][s][1] = (f16x2){ (f16)q0.z, (f16)q0.w };
        srcv[1][s][2] = (f16x2){ (f16)q1.x, (f16)q1.y };
        srcv[1][s][3] = (f16x2){ (f16)q1.z, (f16)q1.w };
    }

    // ---- main loop: LDS-free, barrier-free; 4-buffer register ring
    const char* gw = reinterpret_cast<const char*>(w2f)
                   + (size_t)kq * 16 * 8192 + wc * 4096 + lane * 16;

    f16x8 b0[4], b1[4], b2[4], b3[4];
    f32x16 acc0 = {}, acc1 = {};

    #define LOADIT(buf, itw) do { if ((itw) < 16) {                       \
        const char* _p = gw + (itw) * 8192;                               \
        buf[0] = *reinterpret_cast<const f16x8*>(_p);                     \
        buf[1] = *reinterpret_cast<const f16x8*>(_p + 1024);              \
        buf[2] = *reinterpret_cast<const f16x8*>(_p + 2048);              \
        buf[3] = *reinterpret_cast<const f16x8*>(_p + 3072);              \
    } } while (0)

    #define COMPIT(buf, iti) do {                                         \
        const f16x2 _c0 = bp0[iti];                                       \
        const f16x2 _c1 = bp1[iti];                                       \
        _Pragma("unroll")                                                 \
        for (int s = 0; s < 4; ++s) {                                     \
            H8 _a0, _a1;                                                  \
            _Pragma("unroll")                                             \
            for (int t = 0; t < 4; ++t) {                                 \
                _a0.v2[t] = _c0 * srcv[0][s][t];                          \
                _a1.v2[t] = _c1 * srcv[1][s][t];                          \
            }                                                             \
            acc0 = __builtin_amdgcn_mfma_f32_32x32x16_f16(_a0.v8, buf[s], acc0, 0, 0, 0); \
            acc1 = __builtin_amdgcn_mfma_f32_32x32x16_f16(_a1.v8, buf[s], acc1, 0, 0, 0); \
        }                                                                 \
    } while (0)

    LOADIT(b0, 0); LOADIT(b1, 1); LOADIT(b2, 2);

    #pragma unroll
    for (int it = 0; it < 16; it += 4) {
        LOADIT(b3, it + 3);
        COMPIT(b0, it + 0);
        LOADIT(b0, it + 4);
        COMPIT(b1, it + 1);
        LOADIT(b1, it + 5);
        COMPIT(b2, it + 2);
        LOADIT(b2, it + 6);
        COMPIT(b3, it + 3);
    }

    // ---- epilogue: all waves store partials (swizzled, conflict-free),
    // one barrier, all 512 threads reduce + write C coalesced.
    {
        const unsigned wbase = (unsigned)w * 8192u;
        const unsigned so = swz16((unsigned)lane);
        #pragma unroll
        for (int g = 0; g < 4; ++g) {
            float4 v0 = { acc0[4*g+0], acc0[4*g+1], acc0[4*g+2], acc0[4*g+3] };
            *reinterpret_cast<float4*>(smem + wbase + g*1024 + so) = v0;
            float4 v1 = { acc1[4*g+0], acc1[4*g+1], acc1[4*g+2], acc1[4*g+3] };
            *reinterpret_cast<float4*>(smem + wbase + (g+4)*1024 + so) = v1;
        }
    }
    __syncthreads();
    {
        // thread t: column c = t&63, row group rb = t>>6 -> rows 32a+8g+{0..7}
        const int c  = tid & 63;
        const int rb = tid >> 6;
        const int a  = rb >> 2, g = rb & 3;
        const unsigned colb = (unsigned)(c & 31);
        const unsigned wcs  = (unsigned)(c >> 5);
        const unsigned o0 = swz16(colb);        // hi=0 lane = colb
        const unsigned o1 = swz16(32u + colb);  // hi=1 lane
        float4 s0 = {0.f,0.f,0.f,0.f}, s1 = {0.f,0.f,0.f,0.f};
        #pragma unroll
        for (int q = 0; q < 4; ++q) {
            const unsigned base = (unsigned)((q*2 + wcs) * 8192 + (a*4+g) * 1024);
            const float4 u0 = *reinterpret_cast<const float4*>(smem + base + o0);
            const float4 u1 = *reinterpret_cast<const float4*>(smem + base + o1);
            s0.x += u0.x; s0.y += u0.y; s0.z += u0.z; s0.w += u0.w;
            s1.x += u1.x; s1.y += u1.y; s1.z += u1.z; s1.w += u1.w;
        }
        float* orow = out + (size_t)(bond0 + 32*a + 8*g) * 64 + c;
        orow[0*64] = s0.x; orow[1*64] = s0.y; orow[2*64] = s0.z; orow[3*64] = s0.w;
        orow[4*64] = s1.x; orow[5*64] = s1.y; orow[6*64] = s1.z; orow[7*64] = s1.w;
    }
    #undef LOADIT
    #undef COMPIT
}

// ---- fallback (ws too small): f32, LDS-staged, correct.
__global__ __launch_bounds__(256) void bond_fallback(
    const float* __restrict__ atom, const float* __restrict__ bond,
    const int* __restrict__ conn, const float* __restrict__ bt,
    float* __restrict__ out)
{
    __shared__ float Wk[4096];
    __shared__ float srcs[4][64];
    __shared__ float bnds[4][64];
    const int blk = blockIdx.x;
    const int e0 = blk * 4;
    const int b = e0 >> 9;
    const int t = threadIdx.x;
    const int il = t & 63, eg = t >> 6;
    const int e = e0 + eg;
    const int ia = conn[e * 2];
    srcs[eg][il] = atom[(size_t)b * (NATOMS * DIM) + (size_t)ia * DIM + il];
    bnds[eg][il] = bond[(size_t)e * DIM + il];
    float acc = 0.f;
    for (int k = 0; k < 64; ++k) {
        __syncthreads();
        #pragma unroll
        for (int c = 0; c < 4; ++c) {
            float4 v = reinterpret_cast<const float4*>(bt + (size_t)k * 4096)[t + c * 256];
            reinterpret_cast<float4*>(Wk)[t + c * 256] = v;
        }
        __syncthreads();
        float s = 0.f;
        #pragma unroll
        for (int j = 0; j < 64; ++j) s += Wk[il * 64 + j] * srcs[eg][j];
        acc += bnds[eg][k] * s;
    }
    out[(size_t)e * DIM + il] = acc;
}

extern "C" void kernel_launch(void* const* d_in, const int* in_sizes, int n_in,
                              void* d_out, int out_size, void* d_ws, size_t ws_size,
                              hipStream_t stream) {
    const float* atom = (const float*)d_in[0];   // (32,256,64) f32
    const float* bond = (const float*)d_in[1];   // (32,512,64) f32
    const int*   conn = (const int*)d_in[2];     // (32,512,2) int32 (narrowed)
    const float* bt   = (const float*)d_in[3];   // (64,4096) f32
    float* out = (float*)d_out;                  // (32,512,64) f32

    if (ws_size >= (size_t)64 * 4096 * sizeof(f16)) {
        f16* w2f = (f16*)d_ws;                   // 512 KB scratch
        prep_w2f<<<128, 256, 0, stream>>>(bt, w2f);
        bond_msg<<<256, 512, 0, stream>>>(atom, bond, conn, w2f, out);
    } else {
        bond_fallback<<<4096, 256, 0, stream>>>(atom, bond, conn, bt, out);
    }
}